// Round 1
// baseline (403.886 us; speedup 1.0000x reference)
//
#include <hip/hip_runtime.h>
#include <hip/hip_bf16.h>
#include <math.h>

#define H_DIM 4096
#define I_DIM 14336
#define HB_DIM 1024
#define SC_K 4300
#define HC_K 716

__device__ __forceinline__ unsigned sortable(float f) {
    unsigned u = __float_as_uint(f);
    return (u & 0x80000000u) ? ~u : (u | 0x80000000u);
}

// Generic wave-per-row GEMV: out[row] = dot(vec, mat[row, :NCOL])
template <int NCOL>
__global__ __launch_bounds__(256) void gemv_kernel(const float* __restrict__ vec,
                                                   const float* __restrict__ mat,
                                                   float* __restrict__ out, int nrows) {
    int w = threadIdx.x >> 6, lane = threadIdx.x & 63;
    int row = blockIdx.x * 4 + w;
    if (row >= nrows) return;
    const float* mr = mat + (size_t)row * NCOL;
    float s = 0.f;
#pragma unroll 4
    for (int c = 0; c < NCOL; c += 256) {
        int cc = c + lane * 4;
        float4 m = *(const float4*)(mr + cc);
        float4 v = *(const float4*)(vec + cc);
        s += m.x * v.x + m.y * v.y + m.z * v.z + m.w * v.w;
    }
#pragma unroll
    for (int o = 32; o >= 1; o >>= 1) s += __shfl_xor(s, o);
    if (lane == 0) out[row] = s;
}

// Single-block radix-select of top HC_K values of h (14336 floats),
// set flags for them plus all x_topk indices. Deterministic; ties at the
// exact threshold value resolved toward lowest index (matches stable top_k).
__global__ __launch_bounds__(1024) void select_kernel(const float* __restrict__ h,
                                                      const int* __restrict__ x_topk,
                                                      int* __restrict__ flags) {
    __shared__ unsigned bins[2048];
    __shared__ int s_b1, s_b2, s_b3;
    __shared__ unsigned s_above1, s_above2, s_above3;
    int tid = threadIdx.x;

    for (int i = tid; i < I_DIM; i += 1024) flags[i] = 0;
    for (int i = tid; i < 2048; i += 1024) bins[i] = 0;
    __syncthreads();

    // pass 1: top 11 bits
    for (int i = tid; i < I_DIM; i += 1024) {
        unsigned u = sortable(h[i]);
        atomicAdd(&bins[u >> 21], 1u);
    }
    __syncthreads();
    if (tid == 0) {
        unsigned cum = 0; int b = 2047;
        for (; b >= 0; --b) { unsigned c = bins[b]; if (cum + c >= HC_K) break; cum += c; }
        s_b1 = b; s_above1 = cum;
    }
    __syncthreads();
    int b1 = s_b1; unsigned above1 = s_above1;

    // pass 2: middle 11 bits among bin b1
    for (int i = tid; i < 2048; i += 1024) bins[i] = 0;
    __syncthreads();
    for (int i = tid; i < I_DIM; i += 1024) {
        unsigned u = sortable(h[i]);
        if ((int)(u >> 21) == b1) atomicAdd(&bins[(u >> 10) & 0x7FF], 1u);
    }
    __syncthreads();
    if (tid == 0) {
        unsigned need = HC_K - above1; unsigned cum = 0; int b = 2047;
        for (; b >= 0; --b) { unsigned c = bins[b]; if (cum + c >= need) break; cum += c; }
        s_b2 = b; s_above2 = above1 + cum;
    }
    __syncthreads();
    int b2 = s_b2; unsigned above2 = s_above2;

    // pass 3: low 10 bits
    for (int i = tid; i < 1024; i += 1024) bins[i] = 0;
    __syncthreads();
    for (int i = tid; i < I_DIM; i += 1024) {
        unsigned u = sortable(h[i]);
        if ((int)(u >> 21) == b1 && (int)((u >> 10) & 0x7FF) == b2)
            atomicAdd(&bins[u & 0x3FF], 1u);
    }
    __syncthreads();
    if (tid == 0) {
        unsigned need = HC_K - above2; unsigned cum = 0; int b = 1023;
        for (; b >= 0; --b) { unsigned c = bins[b]; if (cum + c >= need) break; cum += c; }
        s_b3 = b; s_above3 = above2 + cum;
    }
    __syncthreads();
    unsigned T = ((unsigned)b1 << 21) | ((unsigned)b2 << 10) | (unsigned)s_b3;
    unsigned G = s_above3;  // count strictly greater than T

    for (int i = tid; i < I_DIM; i += 1024) {
        unsigned u = sortable(h[i]);
        if (u > T) flags[i] = 1;
    }
    __syncthreads();
    if (tid == 0) {
        int need = HC_K - (int)G;
        for (int i = 0; i < I_DIM && need > 0; ++i) {
            if (sortable(h[i]) == T) { flags[i] = 1; --need; }
        }
    }
    // union with x_topk (idempotent writes of 1 — benign races)
    for (int k = tid; k < SC_K; k += 1024) {
        int idx = x_topk[k];
        if (idx >= 0 && idx < I_DIM) flags[idx] = 1;
    }
}

// For each row i: if flagged, tv[i] = silu(dot(x, gate_w[i])) * dot(x, up_w[i]); else 0.
__global__ __launch_bounds__(256) void gate_up_tv(const float* __restrict__ x,
                                                  const float* __restrict__ gate_w,
                                                  const float* __restrict__ up_w,
                                                  const int* __restrict__ flags,
                                                  float* __restrict__ tv) {
    int w = threadIdx.x >> 6, lane = threadIdx.x & 63;
    int row = blockIdx.x * 4 + w;
    if (row >= I_DIM) return;
    if (!flags[row]) { if (lane == 0) tv[row] = 0.f; return; }
    const float* gr = gate_w + (size_t)row * H_DIM;
    const float* ur = up_w + (size_t)row * H_DIM;
    float gs = 0.f, us = 0.f;
#pragma unroll 4
    for (int c = 0; c < H_DIM; c += 256) {
        int cc = c + lane * 4;
        float4 xv = *(const float4*)(x + cc);
        float4 g = *(const float4*)(gr + cc);
        float4 u = *(const float4*)(ur + cc);
        gs += g.x * xv.x + g.y * xv.y + g.z * xv.z + g.w * xv.w;
        us += u.x * xv.x + u.y * xv.y + u.z * xv.z + u.w * xv.w;
    }
#pragma unroll
    for (int o = 32; o >= 1; o >>= 1) {
        gs += __shfl_xor(gs, o);
        us += __shfl_xor(us, o);
    }
    if (lane == 0) {
        float s = gs / (1.f + expf(-gs));  // silu
        tv[row] = s * us;
    }
}

extern "C" void kernel_launch(void* const* d_in, const int* in_sizes, int n_in,
                              void* d_out, int out_size, void* d_ws, size_t ws_size,
                              hipStream_t stream) {
    const float* x      = (const float*)d_in[0];
    const int*   x_topk = (const int*)d_in[1];
    const float* gate_w = (const float*)d_in[2];
    const float* up_w   = (const float*)d_in[3];
    const float* down_w = (const float*)d_in[4];
    const float* hw1    = (const float*)d_in[5];
    const float* hw2    = (const float*)d_in[6];
    float* out = (float*)d_out;

    float* ws    = (float*)d_ws;
    float* h1    = ws;                       // 1024
    float* h     = ws + 1024;                // 14336
    float* tv    = ws + 1024 + I_DIM;        // 14336
    int*   flags = (int*)(ws + 1024 + 2 * I_DIM);  // 14336 ints

    // h1 = x @ helper_w1.T   (1024 rows of 4096)
    gemv_kernel<H_DIM><<<HB_DIM / 4, 256, 0, stream>>>(x, hw1, h1, HB_DIM);
    // h = h1 @ helper_w2.T   (14336 rows of 1024)
    gemv_kernel<HB_DIM><<<I_DIM / 4, 256, 0, stream>>>(h1, hw2, h, I_DIM);
    // top-716 of h, union with x_topk → flags
    select_kernel<<<1, 1024, 0, stream>>>(h, x_topk, flags);
    // tv[i] = silu(x·gate_w[i]) * (x·up_w[i]) for flagged i, else 0
    gate_up_tv<<<I_DIM / 4, 256, 0, stream>>>(x, gate_w, up_w, flags, tv);
    // out = tv @ down_w.T rows: out[h] = dot(down_w[h,:], tv)  (dense, tv has zeros)
    gemv_kernel<I_DIM><<<H_DIM / 4, 256, 0, stream>>>(tv, down_w, out, H_DIM);
}

// Round 2
// 124.959 us; speedup vs baseline: 3.2321x; 3.2321x over previous
//
#include <hip/hip_runtime.h>
#include <hip/hip_bf16.h>
#include <math.h>

#define H_DIM 4096
#define I_DIM 14336
#define HB_DIM 1024
#define SC_K 4300
#define HC_K 716

__device__ __forceinline__ unsigned sortable(float f) {
    unsigned u = __float_as_uint(f);
    return (u & 0x80000000u) ? ~u : (u | 0x80000000u);
}

// Generic wave-per-row GEMV: out[row] = dot(vec, mat[row, :NCOL])
template <int NCOL>
__global__ __launch_bounds__(256) void gemv_kernel(const float* __restrict__ vec,
                                                   const float* __restrict__ mat,
                                                   float* __restrict__ out, int nrows) {
    int w = threadIdx.x >> 6, lane = threadIdx.x & 63;
    int row = blockIdx.x * 4 + w;
    if (row >= nrows) return;
    const float* mr = mat + (size_t)row * NCOL;
    float s = 0.f;
#pragma unroll 4
    for (int c = 0; c < NCOL; c += 256) {
        int cc = c + lane * 4;
        float4 m = *(const float4*)(mr + cc);
        float4 v = *(const float4*)(vec + cc);
        s += m.x * v.x + m.y * v.y + m.z * v.z + m.w * v.w;
    }
#pragma unroll
    for (int o = 32; o >= 1; o >>= 1) s += __shfl_xor(s, o);
    if (lane == 0) out[row] = s;
}

// Single-block radix-select of top HC_K values of h (14336 floats), fully
// parallel: LDS histogram + Hillis-Steele scan per pass, parallel tie-break
// (lowest index wins — matches stable jax.lax.top_k), then union with x_topk.
__global__ __launch_bounds__(1024) void select_kernel(const float* __restrict__ h,
                                                      const int* __restrict__ x_topk,
                                                      int* __restrict__ flags) {
    __shared__ unsigned bins[2048];
    __shared__ unsigned tmp[2048];
    __shared__ int tie_idx[2048];
    __shared__ int s_tie_cnt;
    __shared__ int s_b, s_above;
    int tid = threadIdx.x;

    for (int i = tid; i < I_DIM; i += 1024) flags[i] = 0;

    int b1 = 0, b2 = 0, b3 = 0;
    int above = 0;  // count of elements strictly greater than current prefix

    // ---------- three radix passes: bits [31:21], [20:10], [9:0] ----------
    for (int pass = 0; pass < 3; ++pass) {
        int nb = (pass == 2) ? 1024 : 2048;
        for (int i = tid; i < nb; i += 1024) bins[i] = 0;
        __syncthreads();
        for (int i = tid; i < I_DIM; i += 1024) {
            unsigned u = sortable(h[i]);
            bool in_subset =
                (pass == 0) ? true :
                (pass == 1) ? ((int)(u >> 21) == b1)
                            : ((int)(u >> 21) == b1 && (int)((u >> 10) & 0x7FF) == b2);
            if (in_subset) {
                unsigned key = (pass == 0) ? (u >> 21)
                             : (pass == 1) ? ((u >> 10) & 0x7FF)
                                           : (u & 0x3FF);
                atomicAdd(&bins[key], 1u);
            }
        }
        __syncthreads();
        // inclusive prefix scan of bins[0..nb)
        for (int off = 1; off < nb; off <<= 1) {
            for (int i = tid; i < nb; i += 1024)
                tmp[i] = bins[i] + ((i >= off) ? bins[i - off] : 0u);
            __syncthreads();
            for (int i = tid; i < nb; i += 1024) bins[i] = tmp[i];
            __syncthreads();
        }
        unsigned total = bins[nb - 1];
        unsigned need = (unsigned)(HC_K - above);
        // find bin b: count(bins > b) < need <= count(bins >= b)
        for (int i = tid; i < nb; i += 1024) {
            unsigned Pb = bins[i];
            unsigned Pbm1 = (i > 0) ? bins[i - 1] : 0u;
            if (total - Pb < need && total - Pbm1 >= need) {
                s_b = i;
                s_above = above + (int)(total - Pb);
            }
        }
        __syncthreads();
        if (pass == 0) b1 = s_b;
        else if (pass == 1) b2 = s_b;
        else b3 = s_b;
        above = s_above;
        __syncthreads();
    }

    unsigned T = ((unsigned)b1 << 21) | ((unsigned)b2 << 10) | (unsigned)b3;
    int need = HC_K - above;  // ties to take, in increasing index order

    if (tid == 0) s_tie_cnt = 0;
    __syncthreads();
    for (int i = tid; i < I_DIM; i += 1024) {
        unsigned u = sortable(h[i]);
        if (u > T) flags[i] = 1;
        else if (u == T) {
            int p = atomicAdd(&s_tie_cnt, 1);
            if (p < 2048) tie_idx[p] = i;
        }
    }
    __syncthreads();
    int C = s_tie_cnt; if (C > 2048) C = 2048;
    for (int m = tid; m < C; m += 1024) {
        int my = tie_idx[m];
        int rank = 0;
        for (int j = 0; j < C; ++j) rank += (tie_idx[j] < my) ? 1 : 0;
        if (rank < need) flags[my] = 1;
    }
    // union with x_topk (idempotent writes of 1)
    for (int k = tid; k < SC_K; k += 1024) {
        int idx = x_topk[k];
        if ((unsigned)idx < (unsigned)I_DIM) flags[idx] = 1;
    }
}

// For each row i: if flagged, tv[i] = silu(dot(x, gate_w[i])) * dot(x, up_w[i]); else 0.
__global__ __launch_bounds__(256) void gate_up_tv(const float* __restrict__ x,
                                                  const float* __restrict__ gate_w,
                                                  const float* __restrict__ up_w,
                                                  const int* __restrict__ flags,
                                                  float* __restrict__ tv) {
    int w = threadIdx.x >> 6, lane = threadIdx.x & 63;
    int row = blockIdx.x * 4 + w;
    if (row >= I_DIM) return;
    if (!flags[row]) { if (lane == 0) tv[row] = 0.f; return; }
    const float* gr = gate_w + (size_t)row * H_DIM;
    const float* ur = up_w + (size_t)row * H_DIM;
    float gs = 0.f, us = 0.f;
#pragma unroll 4
    for (int c = 0; c < H_DIM; c += 256) {
        int cc = c + lane * 4;
        float4 xv = *(const float4*)(x + cc);
        float4 g = *(const float4*)(gr + cc);
        float4 u = *(const float4*)(ur + cc);
        gs += g.x * xv.x + g.y * xv.y + g.z * xv.z + g.w * xv.w;
        us += u.x * xv.x + u.y * xv.y + u.z * xv.z + u.w * xv.w;
    }
#pragma unroll
    for (int o = 32; o >= 1; o >>= 1) {
        gs += __shfl_xor(gs, o);
        us += __shfl_xor(us, o);
    }
    if (lane == 0) {
        float s = gs / (1.f + expf(-gs));  // silu
        tv[row] = s * us;
    }
}

extern "C" void kernel_launch(void* const* d_in, const int* in_sizes, int n_in,
                              void* d_out, int out_size, void* d_ws, size_t ws_size,
                              hipStream_t stream) {
    const float* x      = (const float*)d_in[0];
    const int*   x_topk = (const int*)d_in[1];
    const float* gate_w = (const float*)d_in[2];
    const float* up_w   = (const float*)d_in[3];
    const float* down_w = (const float*)d_in[4];
    const float* hw1    = (const float*)d_in[5];
    const float* hw2    = (const float*)d_in[6];
    float* out = (float*)d_out;

    float* ws    = (float*)d_ws;
    float* h1    = ws;                       // 1024
    float* h     = ws + 1024;                // 14336
    float* tv    = ws + 1024 + I_DIM;        // 14336
    int*   flags = (int*)(ws + 1024 + 2 * I_DIM);  // 14336 ints

    // h1 = x @ helper_w1.T   (1024 rows of 4096)
    gemv_kernel<H_DIM><<<HB_DIM / 4, 256, 0, stream>>>(x, hw1, h1, HB_DIM);
    // h = h1 @ helper_w2.T   (14336 rows of 1024)
    gemv_kernel<HB_DIM><<<I_DIM / 4, 256, 0, stream>>>(h1, hw2, h, I_DIM);
    // top-716 of h, union with x_topk → flags
    select_kernel<<<1, 1024, 0, stream>>>(h, x_topk, flags);
    // tv[i] = silu(x·gate_w[i]) * (x·up_w[i]) for flagged i, else 0
    gate_up_tv<<<I_DIM / 4, 256, 0, stream>>>(x, gate_w, up_w, flags, tv);
    // out = tv @ down_w.T rows: out[h] = dot(down_w[h,:], tv)  (dense, tv has zeros)
    gemv_kernel<I_DIM><<<H_DIM / 4, 256, 0, stream>>>(tv, down_w, out, H_DIM);
}

// Round 3
// 112.285 us; speedup vs baseline: 3.5970x; 1.1129x over previous
//
#include <hip/hip_runtime.h>
#include <hip/hip_bf16.h>
#include <math.h>

#define H_DIM 4096
#define I_DIM 14336
#define HB_DIM 1024
#define SC_K 4300
#define HC_K 716

__device__ __forceinline__ unsigned sortable(float f) {
    unsigned u = __float_as_uint(f);
    return (u & 0x80000000u) ? ~u : (u | 0x80000000u);
}

// Generic wave-per-row GEMV: out[row] = dot(vec, mat[row, :NCOL])
template <int NCOL>
__global__ __launch_bounds__(256) void gemv_kernel(const float* __restrict__ vec,
                                                   const float* __restrict__ mat,
                                                   float* __restrict__ out, int nrows) {
    int w = threadIdx.x >> 6, lane = threadIdx.x & 63;
    int row = blockIdx.x * 4 + w;
    if (row >= nrows) return;
    const float* mr = mat + (size_t)row * NCOL;
    float s = 0.f;
#pragma unroll 4
    for (int c = 0; c < NCOL; c += 256) {
        int cc = c + lane * 4;
        float4 m = *(const float4*)(mr + cc);
        float4 v = *(const float4*)(vec + cc);
        s += m.x * v.x + m.y * v.y + m.z * v.z + m.w * v.w;
    }
#pragma unroll
    for (int o = 32; o >= 1; o >>= 1) s += __shfl_xor(s, o);
    if (lane == 0) out[row] = s;
}

// h1 GEMV with 2 waves per row (2 rows per 256-thread block) for occupancy.
__global__ __launch_bounds__(256) void gemv_h1(const float* __restrict__ x,
                                               const float* __restrict__ w1,
                                               float* __restrict__ h1) {
    __shared__ float ps[4];
    int wv = threadIdx.x >> 6, lane = threadIdx.x & 63;
    int row = blockIdx.x * 2 + (wv >> 1);
    int half = wv & 1;
    const float* mr = w1 + (size_t)row * H_DIM + half * 2048;
    const float* vr = x + half * 2048;
    float s = 0.f;
#pragma unroll
    for (int c = 0; c < 2048; c += 256) {
        int cc = c + lane * 4;
        float4 m = *(const float4*)(mr + cc);
        float4 v = *(const float4*)(vr + cc);
        s += m.x * v.x + m.y * v.y + m.z * v.z + m.w * v.w;
    }
#pragma unroll
    for (int o = 32; o >= 1; o >>= 1) s += __shfl_xor(s, o);
    if (lane == 0) ps[wv] = s;
    __syncthreads();
    if (threadIdx.x < 2)
        h1[blockIdx.x * 2 + threadIdx.x] = ps[2 * threadIdx.x] + ps[2 * threadIdx.x + 1];
}

// Single-block radix-select of top HC_K of h: keys cached in registers,
// two-level wave-shfl scans (no Hillis-Steele), parallel tie-break
// (lowest index wins — matches stable jax.lax.top_k), union with x_topk.
__global__ __launch_bounds__(1024) void select_kernel(const float* __restrict__ h,
                                                      const int* __restrict__ x_topk,
                                                      int* __restrict__ flags) {
    __shared__ unsigned bins[2048];
    __shared__ unsigned wpart[16];
    __shared__ int s_b, s_above;
    __shared__ int s_tie_cnt;
    __shared__ int tie_idx[2048];
    int tid = threadIdx.x;
    int lane = tid & 63, wid = tid >> 6;

    unsigned key[14];
#pragma unroll
    for (int j = 0; j < 14; ++j) key[j] = sortable(h[j * 1024 + tid]);

    for (int i = tid; i < I_DIM; i += 1024) flags[i] = 0;
    if (tid == 0) s_tie_cnt = 0;

    int b1 = 0, b2 = 0;
    int above = 0;  // elements strictly greater than current prefix

    for (int pass = 0; pass < 3; ++pass) {
        int nb = (pass == 2) ? 1024 : 2048;
        bins[tid] = 0;
        if (nb == 2048) bins[tid + 1024] = 0;
        __syncthreads();
#pragma unroll
        for (int j = 0; j < 14; ++j) {
            unsigned u = key[j];
            bool in_sub = (pass == 0) ||
                          ((pass == 1) ? ((int)(u >> 21) == b1)
                                       : ((int)(u >> 21) == b1 && (int)((u >> 10) & 0x7FF) == b2));
            if (in_sub) {
                unsigned k = (pass == 0) ? (u >> 21)
                           : (pass == 1) ? ((u >> 10) & 0x7FF)
                                         : (u & 0x3FF);
                atomicAdd(&bins[k], 1u);
            }
        }
        __syncthreads();
        // thread t owns bins[2t], bins[2t+1] (zero beyond nb)
        unsigned c0 = (2 * tid < nb) ? bins[2 * tid] : 0u;
        unsigned c1 = (2 * tid + 1 < nb) ? bins[2 * tid + 1] : 0u;
        unsigned s = c0 + c1;
        // wave inclusive scan
        unsigned incl = s;
#pragma unroll
        for (int o = 1; o < 64; o <<= 1) {
            unsigned v = __shfl_up(incl, o);
            if (lane >= o) incl += v;
        }
        if (lane == 63) wpart[wid] = incl;
        __syncthreads();
        if (wid == 0 && lane < 16) {
            unsigned p = wpart[lane];
#pragma unroll
            for (int o = 1; o < 16; o <<= 1) {
                unsigned v = __shfl_up(p, o, 16);
                if (lane >= o) p += v;
            }
            wpart[lane] = p;
        }
        __syncthreads();
        unsigned total = wpart[15];
        unsigned base = (wid > 0 ? wpart[wid - 1] : 0u) + (incl - s);  // exclusive before bin 2t
        unsigned need = (unsigned)(HC_K - above);
        // P(b-1) for b=2t is `base`; P(2t)=base+c0; P(2t+1)=base+c0+c1
        if (2 * tid < nb) {
            unsigned Pm1 = base, P = base + c0;
            if (total - P < need && total - Pm1 >= need) { s_b = 2 * tid; s_above = above + (int)(total - P); }
        }
        if (2 * tid + 1 < nb) {
            unsigned Pm1 = base + c0, P = base + c0 + c1;
            if (total - P < need && total - Pm1 >= need) { s_b = 2 * tid + 1; s_above = above + (int)(total - P); }
        }
        __syncthreads();
        if (pass == 0) b1 = s_b;
        else if (pass == 1) b2 = s_b;
        above = s_above;
        if (pass == 2) {
            unsigned T = ((unsigned)b1 << 21) | ((unsigned)b2 << 10) | (unsigned)s_b;
            int need2 = HC_K - above;  // ties to take, lowest index first
            __syncthreads();
#pragma unroll
            for (int j = 0; j < 14; ++j) {
                unsigned u = key[j];
                int i = j * 1024 + tid;
                if (u > T) flags[i] = 1;
                else if (u == T) {
                    int p = atomicAdd(&s_tie_cnt, 1);
                    if (p < 2048) tie_idx[p] = i;
                }
            }
            __syncthreads();
            int C = s_tie_cnt;
            if (C <= 2048) {
                for (int m = tid; m < C; m += 1024) {
                    int my = tie_idx[m];
                    int rank = 0;
                    for (int j = 0; j < C; ++j) rank += (tie_idx[j] < my) ? 1 : 0;
                    if (rank < need2) flags[my] = 1;
                }
            } else if (tid == 0) {  // degenerate mass-tie fallback (never expected)
                int left = need2;
                for (int i = 0; i < I_DIM && left > 0; ++i)
                    if (sortable(h[i]) == T) { flags[i] = 1; --left; }
            }
        }
        __syncthreads();
    }

    for (int k = tid; k < SC_K; k += 1024) {
        int idx = x_topk[k];
        if ((unsigned)idx < (unsigned)I_DIM) flags[idx] = 1;
    }
}

// For each row i: if flagged, tv[i] = silu(dot(x, gate_w[i])) * dot(x, up_w[i]); else 0.
__global__ __launch_bounds__(256) void gate_up_tv(const float* __restrict__ x,
                                                  const float* __restrict__ gate_w,
                                                  const float* __restrict__ up_w,
                                                  const int* __restrict__ flags,
                                                  float* __restrict__ tv) {
    int w = threadIdx.x >> 6, lane = threadIdx.x & 63;
    int row = blockIdx.x * 4 + w;
    if (row >= I_DIM) return;
    if (!flags[row]) { if (lane == 0) tv[row] = 0.f; return; }
    const float* gr = gate_w + (size_t)row * H_DIM;
    const float* ur = up_w + (size_t)row * H_DIM;
    float gs = 0.f, us = 0.f;
#pragma unroll 4
    for (int c = 0; c < H_DIM; c += 256) {
        int cc = c + lane * 4;
        float4 xv = *(const float4*)(x + cc);
        float4 g = *(const float4*)(gr + cc);
        float4 u = *(const float4*)(ur + cc);
        gs += g.x * xv.x + g.y * xv.y + g.z * xv.z + g.w * xv.w;
        us += u.x * xv.x + u.y * xv.y + u.z * xv.z + u.w * xv.w;
    }
#pragma unroll
    for (int o = 32; o >= 1; o >>= 1) {
        gs += __shfl_xor(gs, o);
        us += __shfl_xor(us, o);
    }
    if (lane == 0) {
        float s = gs / (1.f + expf(-gs));  // silu
        tv[row] = s * us;
    }
}

extern "C" void kernel_launch(void* const* d_in, const int* in_sizes, int n_in,
                              void* d_out, int out_size, void* d_ws, size_t ws_size,
                              hipStream_t stream) {
    const float* x      = (const float*)d_in[0];
    const int*   x_topk = (const int*)d_in[1];
    const float* gate_w = (const float*)d_in[2];
    const float* up_w   = (const float*)d_in[3];
    const float* down_w = (const float*)d_in[4];
    const float* hw1    = (const float*)d_in[5];
    const float* hw2    = (const float*)d_in[6];
    float* out = (float*)d_out;

    float* ws    = (float*)d_ws;
    float* h1    = ws;                       // 1024
    float* h     = ws + 1024;                // 14336
    float* tv    = ws + 1024 + I_DIM;        // 14336
    int*   flags = (int*)(ws + 1024 + 2 * I_DIM);  // 14336 ints

    // h1 = x @ helper_w1.T   (1024 rows of 4096, 2 waves/row)
    gemv_h1<<<HB_DIM / 2, 256, 0, stream>>>(x, hw1, h1);
    // h = h1 @ helper_w2.T   (14336 rows of 1024)
    gemv_kernel<HB_DIM><<<I_DIM / 4, 256, 0, stream>>>(h1, hw2, h, I_DIM);
    // top-716 of h, union with x_topk → flags
    select_kernel<<<1, 1024, 0, stream>>>(h, x_topk, flags);
    // tv[i] = silu(x·gate_w[i]) * (x·up_w[i]) for flagged i, else 0
    gate_up_tv<<<I_DIM / 4, 256, 0, stream>>>(x, gate_w, up_w, flags, tv);
    // out = tv @ down_w.T rows: out[h] = dot(down_w[h,:], tv)  (dense, tv has zeros)
    gemv_kernel<I_DIM><<<H_DIM / 4, 256, 0, stream>>>(tv, down_w, out, H_DIM);
}